// Round 7
// baseline (368.372 us; speedup 1.0000x reference)
//
#include <hip/hip_runtime.h>
#include <math.h>

#define N_SRC 16384
#define M_REF 16384
#define DEMB  256
#define KNN_K 16
#define CAP   96
#define NC    32
#define GB    4.25f
#define CH    0.265625f        // 17/64, exact in fp32
#define NCELLS (NC * NC * NC)
#define KNNB  (N_SRC / 4)      // 4096 knn blocks (4 waves = 4 src each)
#define QB    (N_SRC / 16)     // 1024 q blocks

__device__ __forceinline__ int cell_of(float x) {
    int c = (int)floorf((x + GB) * (1.0f / CH));
    return min(max(c, 0), NC - 1);
}

// ---------------- K1: zero cell cursors + build W_sym ----------------
__global__ void __launch_bounds__(256) zero_wsym_kernel(int* __restrict__ cursor,
                                                        const float* __restrict__ W,
                                                        float* __restrict__ wsym) {
    int b = blockIdx.x, t = threadIdx.x;
    if (b < NCELLS / 256) {
        cursor[b * 256 + t] = 0;
    } else {
        int i = b - NCELLS / 256, j = t;
        float a = (j >= i) ? W[i * DEMB + j] : 0.f;
        float c = (i >= j) ? W[j * DEMB + i] : 0.f;
        wsym[i * DEMB + j] = a + c;
    }
}

// ---------------- K2: histogram of ref cells ----------------
__global__ void __launch_bounds__(256) hist_kernel(const float* __restrict__ rp,
                                                   int* __restrict__ cursor) {
    int i = blockIdx.x * 256 + threadIdx.x;
    int cx = cell_of(rp[i * 3 + 0]);
    int cy = cell_of(rp[i * 3 + 1]);
    int cz = cell_of(rp[i * 3 + 2]);
    atomicAdd(&cursor[(cz * NC + cy) * NC + cx], 1);
}

// ---------------- K3: exclusive scan -> cell_start; cursor := start ----------------
__global__ void __launch_bounds__(1024) scan_kernel(int* __restrict__ cursor,
                                                    int* __restrict__ cell_start) {
    __shared__ int part[1024];
    int t = threadIdx.x;
    int loc[32]; int s = 0;
    #pragma unroll
    for (int i = 0; i < 32; ++i) { loc[i] = s; s += cursor[t * 32 + i]; }
    part[t] = s;
    __syncthreads();
    for (int off = 1; off < 1024; off <<= 1) {
        int add = (t >= off) ? part[t - off] : 0;
        __syncthreads();
        part[t] += add;
        __syncthreads();
    }
    int ex = part[t] - s;
    #pragma unroll
    for (int i = 0; i < 32; ++i) {
        cell_start[t * 32 + i] = ex + loc[i];
        cursor[t * 32 + i]     = ex + loc[i];
    }
    if (t == 1023) cell_start[NCELLS] = part[1023];
}

// ---------------- K4: scatter refs into CSR order ----------------
__global__ void __launch_bounds__(256) scatter_kernel(const float* __restrict__ rp,
        int* __restrict__ cursor, float4* __restrict__ refp4s, int* __restrict__ ridx_s) {
    int i = blockIdx.x * 256 + threadIdx.x;
    float x = rp[i * 3 + 0], y = rp[i * 3 + 1], z = rp[i * 3 + 2];
    int c = (cell_of(z) * NC + cell_of(y)) * NC + cell_of(x);
    int pos = atomicAdd(&cursor[c], 1);
    refp4s[pos] = make_float4(x, y, z, fmaf(x, x, fmaf(y, y, z * z)));
    ridx_s[pos] = i;
}

// ---------------- helpers ----------------
__device__ __forceinline__ float kth16_lane_min(float v, int lane) {
    #pragma unroll
    for (int k = 2; k <= 64; k <<= 1)
        #pragma unroll
        for (int j = k >> 1; j > 0; j >>= 1) {
            float o = __shfl_xor(v, j, 64);
            bool lower = (lane & j) == 0;
            bool up = (lane & k) == 0;
            float mn = fminf(v, o), mx = fmaxf(v, o);
            v = (lower == up) ? mn : mx;
        }
    return __shfl(v, 15, 64);
}

__device__ __forceinline__ void sort64_kv(float& vd, int& vi, int lane) {
    #pragma unroll
    for (int k = 2; k <= 64; k <<= 1)
        #pragma unroll
        for (int j = k >> 1; j > 0; j >>= 1) {
            float od = __shfl_xor(vd, j, 64);
            int   oi = __shfl_xor(vi, j, 64);
            bool keep_min = (((lane & j) == 0) == ((lane & k) == 0));
            bool oless = (od < vd) || (od == vd && oi < vi);
            bool take = (keep_min == oless);
            vd = take ? od : vd;
            vi = take ? oi : vi;
        }
    }

// ---------------- K5: fused grid-KNN (blocks [0,KNNB)) + q-GEMM (rest) ----------------
// KNN: one wave per src. Shell-incremental cube expansion; per round:
//   phase1: per-lane min over NEW cells only -> tau_shell = 16th lane-min
//   tau = min(prev d16, tau_shell)  (sound: gated-out point implies >=16 closer appended)
//   phase2: ballot-append shell points <= tau (no atomics); seed = prev top-16.
//   selection: exact (d2,idx)-lex bitonic top-16; compact into LDS slots 0..15.
// Stop rule (sound, incl. clamped/outlier srcs): d16_true <= min over non-exhausted
// cube faces of distance(src, face plane); unexamined points lie beyond such a face.
__global__ void __launch_bounds__(256) knnq_kernel(
        const float* __restrict__ src_points, const float4* __restrict__ refp4s,
        const int* __restrict__ ridx_s, const int* __restrict__ cell_start,
        float* __restrict__ kd2, int* __restrict__ kidx,
        const float* __restrict__ src_feats, const float* __restrict__ wsym,
        float* __restrict__ q) {
    __shared__ __align__(16) float smem[16 * DEMB];   // 16 KB (q tile / knn candidates)
    int tid = threadIdx.x;

    if (blockIdx.x < KNNB) {
        // ================= KNN part =================
        const float INF = 3.0e38f;
        int wave = tid >> 6, lane = tid & 63;
        float* cdw = smem + wave * CAP;
        int*   cib = (int*)(smem + 4 * CAP);
        int*   ciw = cib + wave * CAP;

        int n = __builtin_amdgcn_readfirstlane(blockIdx.x * 4 + wave);
        float sx = src_points[n * 3 + 0];
        float sy = src_points[n * 3 + 1];
        float sz = src_points[n * 3 + 2];
        float m2x = -2.f * sx, m2y = -2.f * sy, m2z = -2.f * sz;
        float sn2 = fmaf(sx, sx, fmaf(sy, sy, sz * sz));
        int cx = cell_of(sx), cy = cell_of(sy), cz = cell_of(sz);

        int r = (sn2 < 2.f) ? 1 : (sn2 < 7.f) ? 2 : (sn2 < 10.f) ? 3
              : (sn2 < 13.f) ? 5 : 9;
        int px0 = 1, px1 = 0, py0 = 1, py1 = 0, pz0 = 1, pz1 = 0;   // empty prev cube
        int cnt = 0;                    // uniform candidate count
        float d16p = INF;               // current 16th (d2' space)

        while (true) {
            int x0 = max(cx - r, 0), x1 = min(cx + r, NC - 1);
            int y0 = max(cy - r, 0), y1 = min(cy + r, NC - 1);
            int z0 = max(cz - r, 0), z1 = min(cz + r, NC - 1);

            // ---- phase 1: per-lane min over shell ----
            float mind = INF;
            int off = 0, tot = 0;
            for (int zc = z0; zc <= z1; ++zc)
                for (int yc = y0; yc <= y1; ++yc) {
                    int rb = (zc * NC + yc) * NC;
                    bool ip = (zc >= pz0 && zc <= pz1 && yc >= py0 && yc <= py1);
                    int aLo = x0, aHi = ip ? px0 - 1 : x1;
                    if (aLo <= aHi) {
                        int st = cell_start[rb + aLo];
                        int np = cell_start[rb + aHi + 1] - st;
                        int k = lane - (off & 63); if (k < 0) k += 64;
                        for (; k < np; k += 64) {
                            float4 rp = refp4s[st + k];
                            float d = fmaf(rp.x, m2x, rp.w);
                            d = fmaf(rp.y, m2y, d);
                            d = fmaf(rp.z, m2z, d);
                            mind = fminf(mind, d);
                        }
                        off += np; tot += np;
                    }
                    if (ip && px1 + 1 <= x1) {
                        int st = cell_start[rb + px1 + 1];
                        int np = cell_start[rb + x1 + 1] - st;
                        int k = lane - (off & 63); if (k < 0) k += 64;
                        for (; k < np; k += 64) {
                            float4 rp = refp4s[st + k];
                            float d = fmaf(rp.x, m2x, rp.w);
                            d = fmaf(rp.y, m2y, d);
                            d = fmaf(rp.z, m2z, d);
                            mind = fminf(mind, d);
                        }
                        off += np; tot += np;
                    }
                }

            if (tot > 0) {
                float tau = fminf(kth16_lane_min(mind, lane), d16p);
                int cnt0 = cnt;
                // ---- phase 2: ballot append over shell ----
                for (int zc = z0; zc <= z1; ++zc)
                    for (int yc = y0; yc <= y1; ++yc) {
                        int rb = (zc * NC + yc) * NC;
                        bool ip = (zc >= pz0 && zc <= pz1 && yc >= py0 && yc <= py1);
                        #pragma unroll
                        for (int seg = 0; seg < 2; ++seg) {
                            int lo, hi;
                            if (seg == 0) { lo = x0; hi = ip ? px0 - 1 : x1; }
                            else { if (!ip) break; lo = px1 + 1; hi = x1; }
                            if (lo > hi) continue;
                            int st = cell_start[rb + lo];
                            int np = cell_start[rb + hi + 1] - st;
                            int iters = (np + 63) >> 6;
                            for (int it = 0; it < iters; ++it) {
                                int k = it * 64 + lane;
                                bool inr = k < np;
                                float4 rp = refp4s[st + (inr ? k : 0)];
                                float d = fmaf(rp.x, m2x, rp.w);
                                d = fmaf(rp.y, m2y, d);
                                d = fmaf(rp.z, m2z, d);
                                bool pred = inr && (d <= tau);
                                unsigned long long m = __ballot(pred);
                                int pos = cnt + __popcll(m & ((1ull << lane) - 1ull));
                                if (pred && pos < CAP) {
                                    cdw[pos] = d; ciw[pos] = ridx_s[st + k];
                                }
                                cnt += (int)__popcll(m);
                            }
                        }
                    }
                if (cnt > CAP) cnt = CAP;
                // ---- selection + compaction ----
                if (cnt >= KNN_K && cnt > cnt0) {
                    int count = cnt;
                    float vd = (lane < count) ? cdw[lane] : INF;
                    int   vi = (lane < count) ? ciw[lane] : 0x7fffffff;
                    sort64_kv(vd, vi, lane);
                    int done = 64;
                    while (done < count) {
                        if (lane >= 16) {
                            int p = done + (lane - 16);
                            vd = (p < count) ? cdw[p] : INF;
                            vi = (p < count) ? ciw[p] : 0x7fffffff;
                        }
                        sort64_kv(vd, vi, lane);
                        done += 48;
                    }
                    if (lane < KNN_K) { cdw[lane] = vd; ciw[lane] = vi; }
                    cnt = KNN_K;
                    d16p = __shfl(vd, 15, 64);
                }
            }

            // ---- sound stop bound: distance to nearest non-exhausted face ----
            float bound = INF;
            if (x0 > 0)      bound = fminf(bound, sx - (-GB + (float)x0 * CH));
            if (x1 < NC - 1) bound = fminf(bound, (-GB + (float)(x1 + 1) * CH) - sx);
            if (y0 > 0)      bound = fminf(bound, sy - (-GB + (float)y0 * CH));
            if (y1 < NC - 1) bound = fminf(bound, (-GB + (float)(y1 + 1) * CH) - sy);
            if (z0 > 0)      bound = fminf(bound, sz - (-GB + (float)z0 * CH));
            if (z1 < NC - 1) bound = fminf(bound, (-GB + (float)(z1 + 1) * CH) - sz);

            bool fullcube = (x0 == 0 && y0 == 0 && z0 == 0 &&
                             x1 == NC - 1 && y1 == NC - 1 && z1 == NC - 1);
            if (cnt >= KNN_K && d16p + sn2 <= bound * bound * 0.999f) break;
            if (fullcube) break;
            px0 = x0; px1 = x1; py0 = y0; py1 = y1; pz0 = z0; pz1 = z1;
            r += 1 + (r >> 1);
            if (r > NC) r = NC;
        }

        if (lane < KNN_K) {
            kd2[(size_t)n * KNN_K + lane] = cdw[lane] + sn2;
            kidx[(size_t)n * KNN_K + lane] = ciw[lane];
        }
    } else {
        // ================= q-GEMM part: q = src_feats @ W_sym =================
        float (*sf)[DEMB] = (float(*)[DEMB])smem;
        int n0 = (blockIdx.x - KNNB) * 16;
        int c0 = tid & 63;
        int rg = tid >> 6;
        {
            int c = c0 * 4;
            #pragma unroll
            for (int rr = 0; rr < 4; ++rr) {
                int rw = rr * 4 + rg;
                *(float4*)&sf[rw][c] = *(const float4*)&src_feats[(size_t)(n0 + rw) * DEMB + c];
            }
        }
        __syncthreads();

        float acc[4][4];
        #pragma unroll
        for (int rr = 0; rr < 4; ++rr)
            #pragma unroll
            for (int cc = 0; cc < 4; ++cc) acc[rr][cc] = 0.f;

        for (int c4 = 0; c4 < 64; ++c4) {
            float wv[4][4];
            #pragma unroll
            for (int j = 0; j < 4; ++j)
                #pragma unroll
                for (int cc = 0; cc < 4; ++cc)
                    wv[j][cc] = wsym[(size_t)(c4 * 4 + j) * DEMB + c0 + cc * 64];
            #pragma unroll
            for (int rr = 0; rr < 4; ++rr) {
                float4 s4 = *(const float4*)&sf[rg * 4 + rr][c4 * 4];
                #pragma unroll
                for (int cc = 0; cc < 4; ++cc) {
                    float a = acc[rr][cc];
                    a = fmaf(s4.x, wv[0][cc], a);
                    a = fmaf(s4.y, wv[1][cc], a);
                    a = fmaf(s4.z, wv[2][cc], a);
                    a = fmaf(s4.w, wv[3][cc], a);
                    acc[rr][cc] = a;
                }
            }
        }
        #pragma unroll
        for (int rr = 0; rr < 4; ++rr)
            #pragma unroll
            for (int cc = 0; cc < 4; ++cc)
                q[(size_t)(n0 + rg * 4 + rr) * DEMB + (c0 + cc * 64)] = acc[rr][cc];
    }
}

// ---------------- K6: scores, softmax, corres, w ----------------
__global__ void __launch_bounds__(256) score_kernel(const float* __restrict__ q,
                                                    const float* __restrict__ ref_feats,
                                                    const float* __restrict__ ref_points,
                                                    const float* __restrict__ src_points,
                                                    const float* __restrict__ kd2,
                                                    const int* __restrict__ kidx,
                                                    float* __restrict__ out) {
    int wave = threadIdx.x >> 6;
    int lane = threadIdx.x & 63;
    int n = __builtin_amdgcn_readfirstlane(blockIdx.x * 4 + wave);

    float4 qv = *(const float4*)&q[(size_t)n * DEMB + lane * 4];

    int idx[KNN_K]; float d2[KNN_K];
    #pragma unroll
    for (int k = 0; k < KNN_K; ++k) {
        idx[k] = __builtin_amdgcn_readfirstlane(kidx[(size_t)n * KNN_K + k]);
        d2[k]  = kd2[(size_t)n * KNN_K + k];
    }

    float sc[KNN_K];
    #pragma unroll
    for (int k = 0; k < KNN_K; ++k) {
        float4 r = *(const float4*)&ref_feats[(size_t)idx[k] * DEMB + lane * 4];
        float p = fmaf(r.x, qv.x, fmaf(r.y, qv.y, fmaf(r.z, qv.z, r.w * qv.w)));
        #pragma unroll
        for (int off = 1; off < 64; off <<= 1) p += __shfl_xor(p, off, 64);
        sc[k] = p;
    }

    float tv[KNN_K];
    #pragma unroll
    for (int k = 0; k < KNN_K; ++k) {
        float wt = fmaxf(0.f, fmaf(-2.f, d2[k], 1.f));
        tv[k] = sc[k] * wt;
    }
    float m = tv[0];
    #pragma unroll
    for (int k = 1; k < KNN_K; ++k) m = fmaxf(m, tv[k]);
    float e[KNN_K], s = 0.f;
    #pragma unroll
    for (int k = 0; k < KNN_K; ++k) { e[k] = expf(tv[k] - m); s += e[k]; }

    float cxx = 0.f, cyy = 0.f, czz = 0.f;
    #pragma unroll
    for (int k = 0; k < KNN_K; ++k) {
        float rx = ref_points[idx[k] * 3 + 0];
        float ry = ref_points[idx[k] * 3 + 1];
        float rz = ref_points[idx[k] * 3 + 2];
        cxx = fmaf(e[k], rx, cxx);
        cyy = fmaf(e[k], ry, cyy);
        czz = fmaf(e[k], rz, czz);
    }
    float inv = 1.f / s;
    cxx *= inv; cyy *= inv; czz *= inv;

    if (lane == 0) {
        float ssx = src_points[n * 3 + 0];
        float ssy = src_points[n * 3 + 1];
        float ssz = src_points[n * 3 + 2];
        float dx = ssx - cxx, dy = ssy - cyy, dz = ssz - czz;
        float dist = sqrtf(fmaf(dx, dx, fmaf(dy, dy, dz * dz)));
        float w = fmaxf(0.f, fmaf(-2.f, dist, 1.f));
        out[(size_t)n * 3 + 0] = cxx;
        out[(size_t)n * 3 + 1] = cyy;
        out[(size_t)n * 3 + 2] = czz;
        out[(size_t)N_SRC * 3 + n] = w;
    }
}

extern "C" void kernel_launch(void* const* d_in, const int* in_sizes, int n_in,
                              void* d_out, int out_size, void* d_ws, size_t ws_size,
                              hipStream_t stream) {
    const float* ref_points = (const float*)d_in[0];
    const float* src_points = (const float*)d_in[1];
    const float* ref_feats  = (const float*)d_in[2];
    const float* src_feats  = (const float*)d_in[3];
    const float* W          = (const float*)d_in[4];
    float* out = (float*)d_out;

    char* ws = (char*)d_ws;
    float4* refp4s     = (float4*)ws;                 ws += (size_t)M_REF * 16;
    float*  q          = (float*)ws;                  ws += (size_t)N_SRC * DEMB * 4;
    float*  wsym       = (float*)ws;                  ws += (size_t)DEMB * DEMB * 4;
    float*  kd2        = (float*)ws;                  ws += (size_t)N_SRC * KNN_K * 4;
    int*    kidx       = (int*)ws;                    ws += (size_t)N_SRC * KNN_K * 4;
    int*    ridx_s     = (int*)ws;                    ws += (size_t)M_REF * 4;
    int*    cell_start = (int*)ws;                    ws += (size_t)(NCELLS + 4) * 4;
    int*    cursor     = (int*)ws;

    zero_wsym_kernel<<<NCELLS / 256 + DEMB, 256, 0, stream>>>(cursor, W, wsym);
    hist_kernel<<<M_REF / 256, 256, 0, stream>>>(ref_points, cursor);
    scan_kernel<<<1, 1024, 0, stream>>>(cursor, cell_start);
    scatter_kernel<<<M_REF / 256, 256, 0, stream>>>(ref_points, cursor, refp4s, ridx_s);
    knnq_kernel<<<KNNB + QB, 256, 0, stream>>>(src_points, refp4s, ridx_s, cell_start,
                                               kd2, kidx, src_feats, wsym, q);
    score_kernel<<<N_SRC / 4, 256, 0, stream>>>(q, ref_feats, ref_points, src_points,
                                                kd2, kidx, out);
}

// Round 8
// 275.905 us; speedup vs baseline: 1.3351x; 1.3351x over previous
//
#include <hip/hip_runtime.h>
#include <math.h>

#define N_SRC 16384
#define M_REF 16384
#define DEMB  256
#define KNN_K 16
#define CAP   128
#define NC    32
#define GB    4.25f
#define CH    0.265625f        // 17/64, exact in fp32
#define NCELLS (NC * NC * NC)
#define NSLAB  (NC * NC)
#define KNNB   (N_SRC / 16)    // 1024 knn blocks (4 waves x 4 srcs)
#define QB     (N_SRC / 16)    // 1024 q blocks

__device__ __forceinline__ int cell_of(float x) {
    int c = (int)floorf((x + GB) * (1.0f / CH));
    return min(max(c, 0), NC - 1);
}

// ---------------- K1: zero both cursors + build W_sym ----------------
__global__ void __launch_bounds__(256) setup_kernel(int* __restrict__ rcur,
                                                    int* __restrict__ scur,
                                                    const float* __restrict__ W,
                                                    float* __restrict__ wsym) {
    int b = blockIdx.x, t = threadIdx.x;
    if (b < 128) {
        rcur[b * 256 + t] = 0;
    } else if (b < 256) {
        scur[(b - 128) * 256 + t] = 0;
    } else {
        int i = b - 256, j = t;
        float a = (j >= i) ? W[i * DEMB + j] : 0.f;
        float c = (i >= j) ? W[j * DEMB + i] : 0.f;
        wsym[i * DEMB + j] = a + c;
    }
}

// ---------------- K2: histograms (ref blocks 0..63, src blocks 64..127) ----------------
__global__ void __launch_bounds__(256) hist_kernel(const float* __restrict__ rp,
                                                   const float* __restrict__ sp,
                                                   int* __restrict__ rcur,
                                                   int* __restrict__ scur) {
    int b = blockIdx.x, t = threadIdx.x;
    const float* p = (b < 64) ? rp : sp;
    int* cur = (b < 64) ? rcur : scur;
    int i = (b & 63) * 256 + t;
    int cx = cell_of(p[i * 3 + 0]);
    int cy = cell_of(p[i * 3 + 1]);
    int cz = cell_of(p[i * 3 + 2]);
    atomicAdd(&cur[(cz * NC + cy) * NC + cx], 1);
}

// ---------------- K3: exclusive scans (block 0 ref, block 1 src) ----------------
__global__ void __launch_bounds__(1024) scan_kernel(int* __restrict__ rcur, int* __restrict__ rcs,
                                                    int* __restrict__ scur, int* __restrict__ scs) {
    int* cur = blockIdx.x ? scur : rcur;
    int* cs  = blockIdx.x ? scs  : rcs;
    __shared__ int part[1024];
    int t = threadIdx.x;
    int loc[32]; int s = 0;
    #pragma unroll
    for (int i = 0; i < 32; ++i) { loc[i] = s; s += cur[t * 32 + i]; }
    part[t] = s;
    __syncthreads();
    for (int off = 1; off < 1024; off <<= 1) {
        int add = (t >= off) ? part[t - off] : 0;
        __syncthreads();
        part[t] += add;
        __syncthreads();
    }
    int ex = part[t] - s;
    #pragma unroll
    for (int i = 0; i < 32; ++i) {
        cs[t * 32 + i]  = ex + loc[i];
        cur[t * 32 + i] = ex + loc[i];
    }
    if (t == 1023) cs[NCELLS] = part[1023];
}

// ---------------- K4: scatter (ref blocks 0..63 -> refp4s, src blocks 64..127) ----------
__global__ void __launch_bounds__(256) scatter_kernel(const float* __restrict__ rp,
        const float* __restrict__ sp, int* __restrict__ rcur, int* __restrict__ scur,
        float4* __restrict__ refp4s, int* __restrict__ ridx,
        float4* __restrict__ srcp4s, int* __restrict__ sidx) {
    int b = blockIdx.x, t = threadIdx.x;
    if (b < 64) {
        int i = b * 256 + t;
        float x = rp[i * 3 + 0], y = rp[i * 3 + 1], z = rp[i * 3 + 2];
        int c = (cell_of(z) * NC + cell_of(y)) * NC + cell_of(x);
        int pos = atomicAdd(&rcur[c], 1);
        refp4s[pos] = make_float4(x, y, z, fmaf(x, x, fmaf(y, y, z * z)));
        ridx[pos] = i;
    } else {
        int i = (b - 64) * 256 + t;
        float x = sp[i * 3 + 0], y = sp[i * 3 + 1], z = sp[i * 3 + 2];
        int c = (cell_of(z) * NC + cell_of(y)) * NC + cell_of(x);
        int pos = atomicAdd(&scur[c], 1);
        srcp4s[pos] = make_float4(x, y, z, fmaf(x, x, fmaf(y, y, z * z)));
        sidx[pos] = i;
    }
}

// ---------------- helpers ----------------
__device__ __forceinline__ float kth16_lane_min(float v, int lane) {
    #pragma unroll
    for (int k = 2; k <= 64; k <<= 1)
        #pragma unroll
        for (int j = k >> 1; j > 0; j >>= 1) {
            float o = __shfl_xor(v, j, 64);
            bool lower = (lane & j) == 0;
            bool up = (lane & k) == 0;
            float mn = fminf(v, o), mx = fmaxf(v, o);
            v = (lower == up) ? mn : mx;
        }
    return __shfl(v, 15, 64);
}

__device__ __forceinline__ void sort64_kv(float& vd, int& vi, int lane) {
    #pragma unroll
    for (int k = 2; k <= 64; k <<= 1)
        #pragma unroll
        for (int j = k >> 1; j > 0; j >>= 1) {
            float od = __shfl_xor(vd, j, 64);
            int   oi = __shfl_xor(vi, j, 64);
            bool keep_min = (((lane & j) == 0) == ((lane & k) == 0));
            bool oless = (od < vd) || (od == vd && oi < vi);
            bool take = (keep_min == oless);
            vd = take ? od : vd;
            vi = take ? oi : vi;
        }
}

// ---------------- K5: tau probe — one wave per sorted src ----------------
// Scan the r=1 cube (expand x2 while <16 points seen) with round-robin lane fill;
// tau' = 16th-smallest lane-min = 16 distinct real distances => sound upper bound
// on the true 16th distance (d2' = |r|^2 - 2 r.s space).
__global__ void __launch_bounds__(256) tau_kernel(const float4* __restrict__ srcp4s,
                                                  const float4* __restrict__ refp4s,
                                                  const int* __restrict__ rcs,
                                                  float* __restrict__ taup) {
    const float INF = 3.0e38f;
    int wave = threadIdx.x >> 6, lane = threadIdx.x & 63;
    int n = __builtin_amdgcn_readfirstlane(blockIdx.x * 4 + wave);
    float4 s4 = srcp4s[n];
    float m2x = -2.f * s4.x, m2y = -2.f * s4.y, m2z = -2.f * s4.z;
    int cx = cell_of(s4.x), cy = cell_of(s4.y), cz = cell_of(s4.z);

    int r = 1;
    float tau;
    while (true) {
        int x0 = max(cx - r, 0), x1 = min(cx + r, NC - 1);
        int y0 = max(cy - r, 0), y1 = min(cy + r, NC - 1);
        int z0 = max(cz - r, 0), z1 = min(cz + r, NC - 1);
        float mind = INF;
        int off = 0, tot = 0;
        for (int zc = z0; zc <= z1; ++zc)
            for (int yc = y0; yc <= y1; ++yc) {
                int rb = (zc * NC + yc) * NC;
                int st = rcs[rb + x0];
                int np = rcs[rb + x1 + 1] - st;
                int k = lane - off; if (k < 0) k += 64;
                for (; k < np; k += 64) {
                    float4 rp = refp4s[st + k];
                    float d = fmaf(rp.x, m2x, rp.w);
                    d = fmaf(rp.y, m2y, d);
                    d = fmaf(rp.z, m2z, d);
                    mind = fminf(mind, d);
                }
                off = (off + np) & 63;
                tot += np;
            }
        bool full = (x0 == 0 && y0 == 0 && z0 == 0 &&
                     x1 == NC - 1 && y1 == NC - 1 && z1 == NC - 1);
        if (tot >= KNN_K || full) { tau = kth16_lane_min(mind, lane); break; }
        r <<= 1;
    }
    if (lane == 0) taup[n] = tau;
}

// ---------------- K6: fused exact KNN (z-slab gated single pass) + q-GEMM ----------------
// KNN blocks [0,KNNB): 4 waves x 4 sorted srcs. Window: slabs [cell(sz-t), cell(sz+t)],
// t = sqrt(tau'+|s|^2); any ref outside has d2 > tau'+|s|^2 >= true d16 (monotone
// clamped-cell argument covers out-of-box points). One contiguous CSR stream,
// ballot append (d' <= tau'), exact (d2,idx)-lex bitonic top-16.
__global__ void __launch_bounds__(256) knnq_kernel(
        const float4* __restrict__ srcp4s, const int* __restrict__ sidx,
        const float4* __restrict__ refp4s, const int* __restrict__ ridx,
        const int* __restrict__ rcs, const float* __restrict__ taup,
        float* __restrict__ kd2, int* __restrict__ kidx,
        const float* __restrict__ src_feats, const float* __restrict__ wsym,
        float* __restrict__ q) {
    __shared__ __align__(16) float smem[4096];   // 16 KB both parts
    int tid = threadIdx.x;

    if (blockIdx.x < KNNB) {
        const float INF = 3.0e38f;
        int wave = tid >> 6, lane = tid & 63;
        float* cdw = smem + wave * (4 * CAP);
        int*   ciw = (int*)(smem + 2048) + wave * (4 * CAP);
        int s0 = __builtin_amdgcn_readfirstlane(blockIdx.x * 16 + wave * 4);

        float m2x[4], m2y[4], m2z[4], sn2[4], tau[4];
        int zlo = NC - 1, zhi = 0;
        #pragma unroll
        for (int b = 0; b < 4; ++b) {
            float4 s4 = srcp4s[s0 + b];
            m2x[b] = -2.f * s4.x; m2y[b] = -2.f * s4.y; m2z[b] = -2.f * s4.z;
            sn2[b] = s4.w;
            tau[b] = taup[s0 + b];
            float t = sqrtf(fmaxf(tau[b] + sn2[b], 0.f));
            zlo = min(zlo, cell_of(s4.z - t));
            zhi = max(zhi, cell_of(s4.z + t));
        }
        int st = rcs[zlo * NSLAB];
        int en = rcs[(zhi + 1) * NSLAB];
        int cnt[4] = {0, 0, 0, 0};
        int iters = (en - st + 63) >> 6;
        for (int it = 0; it < iters; ++it) {
            int k = st + it * 64 + lane;
            bool inr = k < en;
            float4 rp = refp4s[inr ? k : st];
            #pragma unroll
            for (int b = 0; b < 4; ++b) {
                float d = fmaf(rp.x, m2x[b], rp.w);
                d = fmaf(rp.y, m2y[b], d);
                d = fmaf(rp.z, m2z[b], d);
                bool pred = inr && (d <= tau[b]);
                unsigned long long m = __ballot(pred);
                int pos = cnt[b] + (int)__popcll(m & ((1ull << lane) - 1ull));
                if (pred && pos < CAP) {
                    cdw[b * CAP + pos] = d;
                    ciw[b * CAP + pos] = ridx[k];
                }
                cnt[b] += (int)__popcll(m);
            }
        }
        #pragma unroll
        for (int b = 0; b < 4; ++b) {
            int count = min(cnt[b], CAP);
            float vd = (lane < count) ? cdw[b * CAP + lane] : INF;
            int   vi = (lane < count) ? ciw[b * CAP + lane] : 0x7fffffff;
            sort64_kv(vd, vi, lane);
            int done = 64;
            while (done < count) {
                if (lane >= 16) {
                    int p = done + (lane - 16);
                    vd = (p < count) ? cdw[b * CAP + p] : INF;
                    vi = (p < count) ? ciw[b * CAP + p] : 0x7fffffff;
                }
                sort64_kv(vd, vi, lane);
                done += 48;
            }
            int orig = sidx[s0 + b];
            if (lane < KNN_K) {
                kd2[(size_t)orig * KNN_K + lane] = vd + sn2[b];
                kidx[(size_t)orig * KNN_K + lane] = vi;
            }
        }
    } else {
        // ================= q-GEMM: q = src_feats @ W_sym =================
        float (*sf)[DEMB] = (float(*)[DEMB])smem;
        int n0 = (blockIdx.x - KNNB) * 16;
        int c0 = tid & 63;
        int rg = tid >> 6;
        {
            int c = c0 * 4;
            #pragma unroll
            for (int rr = 0; rr < 4; ++rr) {
                int rw = rr * 4 + rg;
                *(float4*)&sf[rw][c] = *(const float4*)&src_feats[(size_t)(n0 + rw) * DEMB + c];
            }
        }
        __syncthreads();

        float acc[4][4];
        #pragma unroll
        for (int rr = 0; rr < 4; ++rr)
            #pragma unroll
            for (int cc = 0; cc < 4; ++cc) acc[rr][cc] = 0.f;

        for (int c4 = 0; c4 < 64; ++c4) {
            float wv[4][4];
            #pragma unroll
            for (int j = 0; j < 4; ++j)
                #pragma unroll
                for (int cc = 0; cc < 4; ++cc)
                    wv[j][cc] = wsym[(size_t)(c4 * 4 + j) * DEMB + c0 + cc * 64];
            #pragma unroll
            for (int rr = 0; rr < 4; ++rr) {
                float4 s4 = *(const float4*)&sf[rg * 4 + rr][c4 * 4];
                #pragma unroll
                for (int cc = 0; cc < 4; ++cc) {
                    float a = acc[rr][cc];
                    a = fmaf(s4.x, wv[0][cc], a);
                    a = fmaf(s4.y, wv[1][cc], a);
                    a = fmaf(s4.z, wv[2][cc], a);
                    a = fmaf(s4.w, wv[3][cc], a);
                    acc[rr][cc] = a;
                }
            }
        }
        #pragma unroll
        for (int rr = 0; rr < 4; ++rr)
            #pragma unroll
            for (int cc = 0; cc < 4; ++cc)
                q[(size_t)(n0 + rg * 4 + rr) * DEMB + (c0 + cc * 64)] = acc[rr][cc];
    }
}

// ---------------- K7: scores, softmax, corres, w ----------------
__global__ void __launch_bounds__(256) score_kernel(const float* __restrict__ q,
                                                    const float* __restrict__ ref_feats,
                                                    const float* __restrict__ ref_points,
                                                    const float* __restrict__ src_points,
                                                    const float* __restrict__ kd2,
                                                    const int* __restrict__ kidx,
                                                    float* __restrict__ out) {
    int wave = threadIdx.x >> 6;
    int lane = threadIdx.x & 63;
    int n = __builtin_amdgcn_readfirstlane(blockIdx.x * 4 + wave);

    float4 qv = *(const float4*)&q[(size_t)n * DEMB + lane * 4];

    int idx[KNN_K]; float d2[KNN_K];
    #pragma unroll
    for (int k = 0; k < KNN_K; ++k) {
        idx[k] = __builtin_amdgcn_readfirstlane(kidx[(size_t)n * KNN_K + k]);
        d2[k]  = kd2[(size_t)n * KNN_K + k];
    }

    float sc[KNN_K];
    #pragma unroll
    for (int k = 0; k < KNN_K; ++k) {
        float4 r = *(const float4*)&ref_feats[(size_t)idx[k] * DEMB + lane * 4];
        float p = fmaf(r.x, qv.x, fmaf(r.y, qv.y, fmaf(r.z, qv.z, r.w * qv.w)));
        #pragma unroll
        for (int off = 1; off < 64; off <<= 1) p += __shfl_xor(p, off, 64);
        sc[k] = p;
    }

    float tv[KNN_K];
    #pragma unroll
    for (int k = 0; k < KNN_K; ++k) {
        float wt = fmaxf(0.f, fmaf(-2.f, d2[k], 1.f));
        tv[k] = sc[k] * wt;
    }
    float m = tv[0];
    #pragma unroll
    for (int k = 1; k < KNN_K; ++k) m = fmaxf(m, tv[k]);
    float e[KNN_K], s = 0.f;
    #pragma unroll
    for (int k = 0; k < KNN_K; ++k) { e[k] = expf(tv[k] - m); s += e[k]; }

    float cxx = 0.f, cyy = 0.f, czz = 0.f;
    #pragma unroll
    for (int k = 0; k < KNN_K; ++k) {
        float rx = ref_points[idx[k] * 3 + 0];
        float ry = ref_points[idx[k] * 3 + 1];
        float rz = ref_points[idx[k] * 3 + 2];
        cxx = fmaf(e[k], rx, cxx);
        cyy = fmaf(e[k], ry, cyy);
        czz = fmaf(e[k], rz, czz);
    }
    float inv = 1.f / s;
    cxx *= inv; cyy *= inv; czz *= inv;

    if (lane == 0) {
        float ssx = src_points[n * 3 + 0];
        float ssy = src_points[n * 3 + 1];
        float ssz = src_points[n * 3 + 2];
        float dx = ssx - cxx, dy = ssy - cyy, dz = ssz - czz;
        float dist = sqrtf(fmaf(dx, dx, fmaf(dy, dy, dz * dz)));
        float w = fmaxf(0.f, fmaf(-2.f, dist, 1.f));
        out[(size_t)n * 3 + 0] = cxx;
        out[(size_t)n * 3 + 1] = cyy;
        out[(size_t)n * 3 + 2] = czz;
        out[(size_t)N_SRC * 3 + n] = w;
    }
}

extern "C" void kernel_launch(void* const* d_in, const int* in_sizes, int n_in,
                              void* d_out, int out_size, void* d_ws, size_t ws_size,
                              hipStream_t stream) {
    const float* ref_points = (const float*)d_in[0];
    const float* src_points = (const float*)d_in[1];
    const float* ref_feats  = (const float*)d_in[2];
    const float* src_feats  = (const float*)d_in[3];
    const float* W          = (const float*)d_in[4];
    float* out = (float*)d_out;

    char* ws = (char*)d_ws;
    float4* refp4s = (float4*)ws;         ws += (size_t)M_REF * 16;
    float4* srcp4s = (float4*)ws;         ws += (size_t)N_SRC * 16;
    float*  q      = (float*)ws;          ws += (size_t)N_SRC * DEMB * 4;
    float*  wsym   = (float*)ws;          ws += (size_t)DEMB * DEMB * 4;
    float*  kd2    = (float*)ws;          ws += (size_t)N_SRC * KNN_K * 4;
    int*    kidx   = (int*)ws;            ws += (size_t)N_SRC * KNN_K * 4;
    int*    ridx   = (int*)ws;            ws += (size_t)M_REF * 4;
    int*    sidx   = (int*)ws;            ws += (size_t)N_SRC * 4;
    int*    rcs    = (int*)ws;            ws += (size_t)(NCELLS + 8) * 4;
    int*    scs    = (int*)ws;            ws += (size_t)(NCELLS + 8) * 4;
    int*    rcur   = (int*)ws;            ws += (size_t)NCELLS * 4;
    int*    scur   = (int*)ws;            ws += (size_t)NCELLS * 4;
    float*  taup   = (float*)ws;

    setup_kernel<<<512, 256, 0, stream>>>(rcur, scur, W, wsym);
    hist_kernel<<<128, 256, 0, stream>>>(ref_points, src_points, rcur, scur);
    scan_kernel<<<2, 1024, 0, stream>>>(rcur, rcs, scur, scs);
    scatter_kernel<<<128, 256, 0, stream>>>(ref_points, src_points, rcur, scur,
                                            refp4s, ridx, srcp4s, sidx);
    tau_kernel<<<N_SRC / 4, 256, 0, stream>>>(srcp4s, refp4s, rcs, taup);
    knnq_kernel<<<KNNB + QB, 256, 0, stream>>>(srcp4s, sidx, refp4s, ridx, rcs, taup,
                                               kd2, kidx, src_feats, wsym, q);
    score_kernel<<<N_SRC / 4, 256, 0, stream>>>(q, ref_feats, ref_points, src_points,
                                                kd2, kidx, out);
}